// Round 12
// baseline (2180.692 us; speedup 1.0000x reference)
//
#include <hip/hip_runtime.h>

#define BB 4
#define NN 16384
#define CC 64
#define NPOINT 1024
#define NSAMPLE 32

#define FPS_T 512
#define NWAVE 8             // FPS_T / 64
#define NCHUNK 256          // 64 points per chunk
#define NCELL 4096          // 16^3 Morton cells

#define REPEAT32(M) M(0) M(1) M(2) M(3) M(4) M(5) M(6) M(7) \
                    M(8) M(9) M(10) M(11) M(12) M(13) M(14) M(15) \
                    M(16) M(17) M(18) M(19) M(20) M(21) M(22) M(23) \
                    M(24) M(25) M(26) M(27) M(28) M(29) M(30) M(31)

// ---------------------------------------------------------------------------
// K1: Pruned FPS, 8 waves (512 threads), 32 chunks/wave, event-driven
// reductions, 4-slot atomic tree, shfl winner select, no global ops in loop.
//  - Morton counting-sort: sb (global float4 x,y,z,orig) + sxy (LDS float2).
//  - Wave wv owns chunks {wv+8k, k<32}; lane L holds u64 key##k =
//    d_bits<<32 | tb<<4 (tb = 0x3FFF-orig, globally unique) — LOOP-CARRIED.
//    z##k pinned ONCE pre-loop (asm output is non-rematerializable).
//    AABB of chunk wv+8k in lane-k registers; cub = upper bound on chunk
//    max d (min over processed centroids of maxdist2) tightens the prune.
//  - Prune: active iff mind2(AABB,c) <= min(prev_wd, cub)*1.001 — exact-
//    conservative no-op skip.
//  - Event-driven: lane best recomputed only when its best's key decreased;
//    wave butterfly only when holder lane's best decreased; unique keys ->
//    no tie paths; first-original-index tie-break exact.
//  - Cross-wave: holder writes coords to wbc dbuf + atomicMax(bkey|wv) into
//    slot4[wv&3] (2-way serialization); ONE barrier; 4 parallel slot reads
//    + 3 compares; coords via speculative wbc[lane&7] read + 3 __shfl.
//  - Centroids buffered in LDS outc[], flushed post-loop.
// Bit-exact: contract(off), (dx*dx+dy*dy)+dz*dz order, min-as-cond-update.
// ---------------------------------------------------------------------------
__global__ __launch_bounds__(FPS_T, 2) void fps_kernel(const float* __restrict__ xyz,
                                                       float* __restrict__ new_xyz,
                                                       float4* __restrict__ sorted) {
    #pragma clang fp contract(off)
    extern __shared__ char smem_raw[];
    float2* sxy  = (float2*)smem_raw;                         // 131072 B
    int*    hist = (int*)(smem_raw + 131072);                 // 16384 B (setup)
    float*  outc = (float*)(smem_raw + 131072);               // 12288 B (alias)
    float4* wbc  = (float4*)(smem_raw + 147456);              // [2][8] 256 B
    unsigned long long* slot4 = (unsigned long long*)(smem_raw + 147712); // [4][4]
    int*    wsum = (int*)(smem_raw + 147840);                 // [8]

    const int b    = blockIdx.x;
    const int tid  = threadIdx.x;
    const int lane = tid & 63;
    const int wv   = tid >> 6;                  // 0..7
    const float* bx = xyz + (size_t)b * NN * 3;
    float4* sb = sorted + (size_t)b * NN;

    // ---------- phase 0a: histogram of Morton cell codes ----------
    #pragma unroll
    for (int j = 0; j < 8; ++j) hist[j * FPS_T + tid] = 0;
    __syncthreads();

    #pragma unroll
    for (int j = 0; j < 32; ++j) {
        const int p = j * FPS_T + tid;
        const float x = bx[p * 3 + 0], y = bx[p * 3 + 1], z = bx[p * 3 + 2];
        int cx = (int)(x * 16.0f); cx = cx > 15 ? 15 : (cx < 0 ? 0 : cx);
        int cy = (int)(y * 16.0f); cy = cy > 15 ? 15 : (cy < 0 ? 0 : cy);
        int cz = (int)(z * 16.0f); cz = cz > 15 ? 15 : (cz < 0 ? 0 : cz);
        int code = 0;
        #pragma unroll
        for (int i = 0; i < 4; ++i)
            code |= (((cx >> i) & 1) << (3 * i)) |
                    (((cy >> i) & 1) << (3 * i + 1)) |
                    (((cz >> i) & 1) << (3 * i + 2));
        atomicAdd(&hist[code], 1);
    }
    __syncthreads();

    // ---------- phase 0b: exclusive scan (8 cells / thread) ----------
    {
        const int b8 = 8 * tid;
        const int h0 = hist[b8+0], h1 = hist[b8+1], h2 = hist[b8+2], h3 = hist[b8+3];
        const int h4 = hist[b8+4], h5 = hist[b8+5], h6 = hist[b8+6], h7 = hist[b8+7];
        const int s  = h0 + h1 + h2 + h3 + h4 + h5 + h6 + h7;
        int v = s;
        #pragma unroll
        for (int o = 1; o < 64; o <<= 1) {
            const int u = __shfl_up(v, o, 64);
            if (lane >= o) v += u;
        }
        if (lane == 63) wsum[wv] = v;
        __syncthreads();
        int base = 0;
        for (int w = 0; w < wv; ++w) base += wsum[w];
        int e = base + v - s;
        hist[b8+0] = e; e += h0;
        hist[b8+1] = e; e += h1;
        hist[b8+2] = e; e += h2;
        hist[b8+3] = e; e += h3;
        hist[b8+4] = e; e += h4;
        hist[b8+5] = e; e += h5;
        hist[b8+6] = e; e += h6;
        hist[b8+7] = e;
    }
    __syncthreads();

    // ---------- phase 0c: scatter to global sb AND LDS sxy ----------
    #pragma unroll
    for (int j = 0; j < 32; ++j) {
        const int p = j * FPS_T + tid;
        const float x = bx[p * 3 + 0], y = bx[p * 3 + 1], z = bx[p * 3 + 2];
        int cx = (int)(x * 16.0f); cx = cx > 15 ? 15 : (cx < 0 ? 0 : cx);
        int cy = (int)(y * 16.0f); cy = cy > 15 ? 15 : (cy < 0 ? 0 : cy);
        int cz = (int)(z * 16.0f); cz = cz > 15 ? 15 : (cz < 0 ? 0 : cz);
        int code = 0;
        #pragma unroll
        for (int i = 0; i < 4; ++i)
            code |= (((cx >> i) & 1) << (3 * i)) |
                    (((cy >> i) & 1) << (3 * i + 1)) |
                    (((cz >> i) & 1) << (3 * i + 2));
        const int slotg = atomicAdd(&hist[code], 1);
        sb[slotg]  = make_float4(x, y, z, __int_as_float(p));
        sxy[slotg] = make_float2(x, y);
    }
    __syncthreads();   // drains scatter stores before readback

    // ---------- phase 0d: per-chunk AABB + z/key preload ----------
#define DECLZ(k) float z##k; unsigned long long key##k;
    REPEAT32(DECLZ)
#undef DECLZ
    float abx0 = 0.f, aby0 = 0.f, abz0 = 0.f, abx1 = 0.f, aby1 = 0.f, abz1 = 0.f;

#define AABBPRE(k) { const int g = wv + ((k) << 3);                       \
    const float4 pt = sb[(g << 6) + lane];                                \
    z##k = pt.z;                                                          \
    key##k = (((unsigned long long)__float_as_uint(1e10f)) << 32) |       \
             ((unsigned long long)(0x3FFFu -                              \
                    (unsigned)__float_as_int(pt.w)) << 4);                \
    float mnx = pt.x, mxx = pt.x, mny = pt.y, mxy = pt.y,                 \
          mnz = pt.z, mxz = pt.z;                                         \
    _Pragma("unroll")                                                     \
    for (int m = 32; m >= 1; m >>= 1) {                                   \
        mnx = fminf(mnx, __shfl_xor(mnx, m, 64));                         \
        mxx = fmaxf(mxx, __shfl_xor(mxx, m, 64));                         \
        mny = fminf(mny, __shfl_xor(mny, m, 64));                         \
        mxy = fmaxf(mxy, __shfl_xor(mxy, m, 64));                         \
        mnz = fminf(mnz, __shfl_xor(mnz, m, 64));                         \
        mxz = fmaxf(mxz, __shfl_xor(mxz, m, 64));                         \
    }                                                                     \
    if (lane == (k)) { abx0 = mnx; abx1 = mxx; aby0 = mny; aby1 = mxy;    \
                       abz0 = mnz; abz1 = mxz; } }
    REPEAT32(AABBPRE)
#undef AABBPRE
    if (tid < 16) slot4[tid] = 0ull;
    __syncthreads();

    // one-time pin: z values become asm outputs -> cannot be rematerialized
    // (sunk as in-loop global reloads); loads can't move past the asm.
    asm volatile("" : "+v"(z0), "+v"(z1), "+v"(z2),  "+v"(z3),
                      "+v"(z4), "+v"(z5), "+v"(z6),  "+v"(z7),
                      "+v"(z8), "+v"(z9), "+v"(z10), "+v"(z11),
                      "+v"(z12), "+v"(z13), "+v"(z14), "+v"(z15));
    asm volatile("" : "+v"(z16), "+v"(z17), "+v"(z18), "+v"(z19),
                      "+v"(z20), "+v"(z21), "+v"(z22), "+v"(z23),
                      "+v"(z24), "+v"(z25), "+v"(z26), "+v"(z27),
                      "+v"(z28), "+v"(z29), "+v"(z30), "+v"(z31));

    // ---------- main loop: ONE barrier per iteration ----------
    unsigned long long bkey = 0ull;   // my lane best (max over key0..31)
    int bestk = 0;
    int holder_ln = 0;                // wave-uniform
    float hx = 0.f, hy = 0.f, hz = 0.f;
    float cub = 1e10f;                // lane k: upper bound on chunk max d

    float ccx = bx[0], ccy = bx[1], ccz = bx[2];
    float prev_wd = 1e10f;

    for (int it = 0; it < NPOINT; ++it) {
        if (tid == 0) {
            outc[it * 3 + 0] = ccx;
            outc[it * 3 + 1] = ccy;
            outc[it * 3 + 2] = ccz;
        }

        // --- AABB prune + cub maintenance (lane L -> chunk wv+8L) ---
        bool active = false;
        if (lane < 32) {
            const float dxl = fmaxf(fmaxf(abx0 - ccx, ccx - abx1), 0.0f);
            const float dyl = fmaxf(fmaxf(aby0 - ccy, ccy - aby1), 0.0f);
            const float dzl = fmaxf(fmaxf(abz0 - ccz, ccz - abz1), 0.0f);
            const float mind2 = dxl * dxl + dyl * dyl + dzl * dzl;
            const float bound = fminf(prev_wd, cub);
            active = !(mind2 > bound * 1.001f);
            if (active) {
                const float dxm = fmaxf(ccx - abx0, abx1 - ccx);
                const float dym = fmaxf(ccy - aby0, aby1 - ccy);
                const float dzm = fmaxf(ccz - abz0, abz1 - ccz);
                const float maxd2 = dxm * dxm + dym * dym + dzm * dzm;
                cub = fminf(cub, maxd2);
            }
        }
        const unsigned amask = (unsigned)(__ballot(active) & 0xFFFFFFFFull);

        bool lredo = false;
#define UPD(k) if (amask & (1u << (k))) {                                 \
            const int g = wv + ((k) << 3);                                \
            const float2 xy = sxy[(g << 6) + lane];                       \
            const float dx = xy.x - ccx;                                  \
            const float dy = xy.y - ccy;                                  \
            const float dz = z##k - ccz;                                  \
            const float t  = (dx * dx + dy * dy) + dz * dz;               \
            const float dold = __uint_as_float((unsigned)(key##k >> 32)); \
            if (t < dold) {                                               \
                key##k = (((unsigned long long)__float_as_uint(t)) << 32) \
                         | (key##k & 0xFFFFFFFFull);                      \
                lredo |= ((k) == bestk);                                  \
            }                                                             \
        }
        if (amask & 0x0000000Fu) { UPD(0)  UPD(1)  UPD(2)  UPD(3)  }
        if (amask & 0x000000F0u) { UPD(4)  UPD(5)  UPD(6)  UPD(7)  }
        if (amask & 0x00000F00u) { UPD(8)  UPD(9)  UPD(10) UPD(11) }
        if (amask & 0x0000F000u) { UPD(12) UPD(13) UPD(14) UPD(15) }
        if (amask & 0x000F0000u) { UPD(16) UPD(17) UPD(18) UPD(19) }
        if (amask & 0x00F00000u) { UPD(20) UPD(21) UPD(22) UPD(23) }
        if (amask & 0x0F000000u) { UPD(24) UPD(25) UPD(26) UPD(27) }
        if (amask & 0xF0000000u) { UPD(28) UPD(29) UPD(30) UPD(31) }
#undef UPD

        // --- per-lane best: recompute only when invalidated ---
        if (lredo) {
            bkey = 0ull; bestk = 0;
#define LM(k) if (key##k > bkey) { bkey = key##k; bestk = (k); }
            REPEAT32(LM)
#undef LM
        }

        // --- wave best: butterfly only when holder's best decreased ---
        const unsigned long long rb = __ballot(lredo);
        if ((rb >> holder_ln) & 1ull) {
            unsigned long long m = bkey;
            #pragma unroll
            for (int s = 32; s >= 1; s >>= 1) {
                const unsigned long long o = __shfl_xor(m, s, 64);
                m = o > m ? o : m;
            }
            holder_ln = __ffsll((long long)__ballot(bkey == m)) - 1;  // unique
            if (lane == holder_ln) {
                const float2 xy = sxy[((wv + (bestk << 3)) << 6) + lane];
                float zz = z0;
#define ZS(k) zz = (bestk == (k)) ? z##k : zz;
                REPEAT32(ZS)
#undef ZS
                hx = xy.x; hy = xy.y; hz = zz;
            }
        }

        // --- cross-wave: coords write + atomicMax into slot (wv&3) ---
        if (lane == holder_ln) {
            wbc[(it & 1) * 8 + wv] = make_float4(hx, hy, hz, 0.0f);
            atomicMax(&slot4[(it & 3) * 4 + (wv & 3)],
                      bkey | (unsigned long long)wv);
        }
        if (tid < 4) slot4[((it + 1) & 3) * 4 + tid] = 0ull;
        __syncthreads();

        // --- winner: 4 parallel slot reads + spec wbc read + shfl select ---
        const float4 spec = wbc[(it & 1) * 8 + (lane & 7)];
        const unsigned long long s0 = slot4[(it & 3) * 4 + 0];
        const unsigned long long s1 = slot4[(it & 3) * 4 + 1];
        const unsigned long long s2 = slot4[(it & 3) * 4 + 2];
        const unsigned long long s3 = slot4[(it & 3) * 4 + 3];
        unsigned long long wk = s0;
        if (s1 > wk) wk = s1;
        if (s2 > wk) wk = s2;
        if (s3 > wk) wk = s3;
        prev_wd = __uint_as_float((unsigned)(wk >> 32));
        const int wwv = (int)(wk & 0x7ull);
        ccx = __shfl(spec.x, wwv, 64);
        ccy = __shfl(spec.y, wwv, 64);
        ccz = __shfl(spec.z, wwv, 64);
    }

    // ---------- flush centroids ----------
    __syncthreads();
    float* outb = new_xyz + (size_t)b * NPOINT * 3;
    #pragma unroll
    for (int j = 0; j < 6; ++j) {
        const int idx = j * FPS_T + tid;
        outb[idx] = outc[idx];
    }
}

// ---------------------------------------------------------------------------
// K2: Ball query. One wave per query; ordered first-32 selection via ballot,
// early exit once 32 found. Exact arithmetic (contract off, rad2 = (float)0.04).
// ---------------------------------------------------------------------------
__global__ __launch_bounds__(256) void ballq_kernel(const float* __restrict__ xyz,
                                                    const float* __restrict__ new_xyz,
                                                    int* __restrict__ gidx) {
    #pragma clang fp contract(off)
    const int lane = threadIdx.x & 63;
    const int q    = blockIdx.x * 4 + (threadIdx.x >> 6);
    const int b    = q >> 10;                  // NPOINT = 1024
    const float* bx = xyz + (size_t)b * NN * 3;
    const float* nx = new_xyz + (size_t)q * 3;
    const float cx = nx[0], cy = nx[1], cz = nx[2];
    const float rad2 = 0.04f;  // f32 cast of python double 0.2**2 — NOT 0.2f*0.2f

    int* out  = gidx + (size_t)q * NSAMPLE;
    int taken = 0;
    int first = NN - 1;

    for (int chunk = 0; chunk < NN / 64 && taken < NSAMPLE; ++chunk) {
        const int   i  = chunk * 64 + lane;
        const float dx = cx - bx[i * 3 + 0];
        const float dy = cy - bx[i * 3 + 1];
        const float dz = cz - bx[i * 3 + 2];
        const float t  = dx * dx + dy * dy + dz * dz;
        const bool ok  = !(t > rad2);
        const unsigned long long m = __ballot(ok);
        const int cnt = __popcll(m);
        if (taken == 0 && cnt > 0) first = chunk * 64 + (__ffsll((long long)m) - 1);
        if (ok) {
            const int rank = taken + __popcll(m & ((1ull << lane) - 1ull));
            if (rank < NSAMPLE) out[rank] = i;
        }
        taken += cnt;
    }
    const int sat = taken < NSAMPLE ? taken : NSAMPLE;
    if (lane >= sat && lane < NSAMPLE) out[lane] = (taken > 0) ? first : (NN - 1);
}

// ---------------------------------------------------------------------------
// K3: gather feats -> LDS, MLP1 (67->64) + relu, MLP2 (64->128) + relu,
// max over the 32 samples. One 256-thread block per query. FMA allowed.
// ---------------------------------------------------------------------------
__global__ __launch_bounds__(256) void mlp_kernel(const float* __restrict__ xyz,
                                                  const float* __restrict__ points,
                                                  const float* __restrict__ w1,
                                                  const float* __restrict__ b1,
                                                  const float* __restrict__ w2,
                                                  const float* __restrict__ b2,
                                                  const float* __restrict__ new_xyz,
                                                  const int*   __restrict__ gidx,
                                                  float* __restrict__ new_points) {
    __shared__ __align__(16) float feats[32][68];
    __shared__ __align__(16) float h1s[32][64];
    __shared__ float pmax[2][128];

    const int q = blockIdx.x;
    const int b = q >> 10;
    const int t = threadIdx.x;

    {
        const int k  = t >> 3;
        const int l8 = t & 7;
        const int gi = gidx[q * 32 + k];
        const float* prow = points + ((size_t)b * NN + gi) * CC;
        const float4 v0 = *(const float4*)(prow + l8 * 8);
        const float4 v1 = *(const float4*)(prow + l8 * 8 + 4);
        *(float4*)&feats[k][4 + l8 * 8] = v0;
        *(float4*)&feats[k][8 + l8 * 8] = v1;
        if (l8 == 0) {
            const float* pr = xyz + ((size_t)b * NN + gi) * 3;
            const float* nr = new_xyz + (size_t)q * 3;
            feats[k][0] = pr[0] - nr[0];
            feats[k][1] = pr[1] - nr[1];
            feats[k][2] = pr[2] - nr[2];
        }
    }

    const int c1 = t & 63;
    float w1r[67];
    #pragma unroll
    for (int j = 0; j < 67; ++j) w1r[j] = w1[c1 * 67 + j];
    const float bb1 = b1[c1];
    __syncthreads();

    const int kg = t >> 6;
    #pragma unroll
    for (int kk = 0; kk < 8; ++kk) {
        const int kr = kg * 8 + kk;
        float acc = bb1;
        acc += feats[kr][0] * w1r[0] + feats[kr][1] * w1r[1] + feats[kr][2] * w1r[2];
        #pragma unroll
        for (int j = 0; j < 64; j += 4) {
            const float4 f = *(const float4*)&feats[kr][4 + j];
            acc += f.x * w1r[3 + j] + f.y * w1r[4 + j] + f.z * w1r[5 + j] + f.w * w1r[6 + j];
        }
        h1s[kr][c1] = fmaxf(acc, 0.0f);
    }

    const int o2 = t & 127;
    const int kh = t >> 7;
    float w2r[64];
    #pragma unroll
    for (int j = 0; j < 64; ++j) w2r[j] = w2[o2 * 64 + j];
    const float bb2 = b2[o2];
    __syncthreads();

    float mx = -INFINITY;
    #pragma unroll
    for (int kk = 0; kk < 16; ++kk) {
        const int kr = kh * 16 + kk;
        float acc = bb2;
        #pragma unroll
        for (int j = 0; j < 64; j += 4) {
            const float4 h = *(const float4*)&h1s[kr][j];
            acc += h.x * w2r[j] + h.y * w2r[j + 1] + h.z * w2r[j + 2] + h.w * w2r[j + 3];
        }
        mx = fmaxf(mx, fmaxf(acc, 0.0f));
    }
    pmax[kh][o2] = mx;
    __syncthreads();
    if (t < 128) {
        new_points[(size_t)q * 128 + t] = fmaxf(pmax[0][t], pmax[1][t]);
    }
}

// ---------------------------------------------------------------------------
extern "C" void kernel_launch(void* const* d_in, const int* in_sizes, int n_in,
                              void* d_out, int out_size, void* d_ws, size_t ws_size,
                              hipStream_t stream) {
    const float* xyz    = (const float*)d_in[0];
    const float* points = (const float*)d_in[1];
    const float* w1     = (const float*)d_in[2];
    const float* b1     = (const float*)d_in[3];
    const float* w2     = (const float*)d_in[4];
    const float* b2     = (const float*)d_in[5];

    float* out_newxyz    = (float*)d_out;
    float* out_newpoints = (float*)d_out + (size_t)BB * NPOINT * 3;
    int*    gidx    = (int*)d_ws;                                   // 512 KB
    float4* sortbuf = (float4*)((char*)d_ws + (size_t)512 * 1024);  // 1 MB

    // LDS map: sxy 131072 | hist/outc alias @131072 (16384) | wbc @147456
    // (256) | slot4 @147712 (128) | wsum @147840 (32)
    const int fps_lds = 147904;
    (void)hipFuncSetAttribute((const void*)fps_kernel,
                              hipFuncAttributeMaxDynamicSharedMemorySize,
                              fps_lds);

    fps_kernel<<<BB, FPS_T, fps_lds, stream>>>(xyz, out_newxyz, sortbuf);
    ballq_kernel<<<(BB * NPOINT) / 4, 256, 0, stream>>>(xyz, out_newxyz, gidx);
    mlp_kernel<<<BB * NPOINT, 256, 0, stream>>>(xyz, points, w1, b1, w2, b2,
                                                out_newxyz, gidx, out_newpoints);
}

// Round 13
// 1624.279 us; speedup vs baseline: 1.3426x; 1.3426x over previous
//
#include <hip/hip_runtime.h>

#define BB 4
#define NN 16384
#define CC 64
#define NPOINT 1024
#define NSAMPLE 32

#define FPS_T 1024
#define NCHUNK 256          // 64 points per chunk
#define NCELL 4096          // 16^3 Morton cells

#define REPEAT16(M) M(0) M(1) M(2) M(3) M(4) M(5) M(6) M(7) \
                    M(8) M(9) M(10) M(11) M(12) M(13) M(14) M(15)

// ---------------------------------------------------------------------------
// K1: Pruned FPS, 16 waves (validated optimum: R11=1.38us/iter vs 8w=2.0,
// 4w=4.9), event-driven reductions, 4-slot atomic tree, shfl winner select,
// no global ops in the iteration loop.
//  - Morton counting-sort: sb (global float4 x,y,z,orig) + sxy (LDS float2).
//  - Wave wv owns chunks {wv+16k}; lane L holds u64 key##k =
//    d_bits<<32 | tb<<4 (tb = 0x3FFF-orig, globally unique) — LOOP-CARRIED.
//    z##k pinned ONCE pre-loop (asm output is non-rematerializable).
//    AABB of chunk wv+16k in lane-k registers; cub = min over processed
//    centroids of maxdist2(AABB,c) >= chunk max d tightens the prune.
//  - Prune: active iff mind2(AABB,c) <= min(prev_wd, cub)*1.001 — exact-
//    conservative no-op skip.
//  - Event-driven: lane best recomputed only when its best's key decreased;
//    wave butterfly only when holder lane's best decreased; unique keys ->
//    no tie paths; first-original-index tie-break exact.
//  - Cross-wave: holder writes coords to wbc dbuf + atomicMax(bkey|wv) into
//    slot4[wv&3] (4-way vs R11's 16-way serialization); ONE barrier; 4
//    parallel slot reads + 3 compares; coords via speculative wbc[lane&15]
//    read + 3 __shfl (overlaps the slot-read latency).
//  - Centroids buffered in LDS outc[], flushed post-loop (keeps vmcnt out
//    of the pre-barrier waitcnt).
// Bit-exact: contract(off), (dx*dx+dy*dy)+dz*dz order, min-as-cond-update.
// ---------------------------------------------------------------------------
__global__ __launch_bounds__(FPS_T) void fps_kernel(const float* __restrict__ xyz,
                                                    float* __restrict__ new_xyz,
                                                    float4* __restrict__ sorted) {
    #pragma clang fp contract(off)
    extern __shared__ char smem_raw[];
    float2* sxy  = (float2*)smem_raw;                         // 131072 B
    int*    hist = (int*)(smem_raw + 131072);                 // 16384 B (setup)
    float*  outc = (float*)(smem_raw + 131072);               // 12288 B (alias)
    float4* wbc  = (float4*)(smem_raw + 147456);              // [2][16] 512 B
    unsigned long long* slot4 = (unsigned long long*)(smem_raw + 147968); // [4][4]
    int*    wsum = (int*)(smem_raw + 148096);                 // [16]

    const int b    = blockIdx.x;
    const int tid  = threadIdx.x;
    const int lane = tid & 63;
    const int wv   = tid >> 6;                  // 0..15
    const float* bx = xyz + (size_t)b * NN * 3;
    float4* sb = sorted + (size_t)b * NN;

    // ---------- phase 0a: histogram of Morton cell codes ----------
    #pragma unroll
    for (int j = 0; j < 4; ++j) hist[j * FPS_T + tid] = 0;
    __syncthreads();

    #pragma unroll
    for (int j = 0; j < 16; ++j) {
        const int p = j * FPS_T + tid;
        const float x = bx[p * 3 + 0], y = bx[p * 3 + 1], z = bx[p * 3 + 2];
        int cx = (int)(x * 16.0f); cx = cx > 15 ? 15 : (cx < 0 ? 0 : cx);
        int cy = (int)(y * 16.0f); cy = cy > 15 ? 15 : (cy < 0 ? 0 : cy);
        int cz = (int)(z * 16.0f); cz = cz > 15 ? 15 : (cz < 0 ? 0 : cz);
        int code = 0;
        #pragma unroll
        for (int i = 0; i < 4; ++i)
            code |= (((cx >> i) & 1) << (3 * i)) |
                    (((cy >> i) & 1) << (3 * i + 1)) |
                    (((cz >> i) & 1) << (3 * i + 2));
        atomicAdd(&hist[code], 1);
    }
    __syncthreads();

    // ---------- phase 0b: exclusive scan ----------
    {
        const int h0 = hist[4 * tid + 0], h1 = hist[4 * tid + 1];
        const int h2 = hist[4 * tid + 2], h3 = hist[4 * tid + 3];
        const int s  = h0 + h1 + h2 + h3;
        int v = s;
        #pragma unroll
        for (int o = 1; o < 64; o <<= 1) {
            const int u = __shfl_up(v, o, 64);
            if (lane >= o) v += u;
        }
        if (lane == 63) wsum[wv] = v;
        __syncthreads();
        int base = 0;
        for (int w = 0; w < wv; ++w) base += wsum[w];
        const int e0 = base + v - s;
        hist[4 * tid + 0] = e0;
        hist[4 * tid + 1] = e0 + h0;
        hist[4 * tid + 2] = e0 + h0 + h1;
        hist[4 * tid + 3] = e0 + h0 + h1 + h2;
    }
    __syncthreads();

    // ---------- phase 0c: scatter to global sb AND LDS sxy ----------
    #pragma unroll
    for (int j = 0; j < 16; ++j) {
        const int p = j * FPS_T + tid;
        const float x = bx[p * 3 + 0], y = bx[p * 3 + 1], z = bx[p * 3 + 2];
        int cx = (int)(x * 16.0f); cx = cx > 15 ? 15 : (cx < 0 ? 0 : cx);
        int cy = (int)(y * 16.0f); cy = cy > 15 ? 15 : (cy < 0 ? 0 : cy);
        int cz = (int)(z * 16.0f); cz = cz > 15 ? 15 : (cz < 0 ? 0 : cz);
        int code = 0;
        #pragma unroll
        for (int i = 0; i < 4; ++i)
            code |= (((cx >> i) & 1) << (3 * i)) |
                    (((cy >> i) & 1) << (3 * i + 1)) |
                    (((cz >> i) & 1) << (3 * i + 2));
        const int slotg = atomicAdd(&hist[code], 1);
        sb[slotg]  = make_float4(x, y, z, __int_as_float(p));
        sxy[slotg] = make_float2(x, y);
    }
    __syncthreads();   // drains scatter stores before readback

    // ---------- phase 0d: per-chunk AABB + z/key preload ----------
#define DECLZ(k) float z##k; unsigned long long key##k;
    REPEAT16(DECLZ)
#undef DECLZ
    float abx0 = 0.f, aby0 = 0.f, abz0 = 0.f, abx1 = 0.f, aby1 = 0.f, abz1 = 0.f;

#define AABBPRE(k) { const int g = wv + ((k) << 4);                       \
    const float4 pt = sb[(g << 6) + lane];                                \
    z##k = pt.z;                                                          \
    key##k = (((unsigned long long)__float_as_uint(1e10f)) << 32) |       \
             ((unsigned long long)(0x3FFFu -                              \
                    (unsigned)__float_as_int(pt.w)) << 4);                \
    float mnx = pt.x, mxx = pt.x, mny = pt.y, mxy = pt.y,                 \
          mnz = pt.z, mxz = pt.z;                                         \
    _Pragma("unroll")                                                     \
    for (int m = 32; m >= 1; m >>= 1) {                                   \
        mnx = fminf(mnx, __shfl_xor(mnx, m, 64));                         \
        mxx = fmaxf(mxx, __shfl_xor(mxx, m, 64));                         \
        mny = fminf(mny, __shfl_xor(mny, m, 64));                         \
        mxy = fmaxf(mxy, __shfl_xor(mxy, m, 64));                         \
        mnz = fminf(mnz, __shfl_xor(mnz, m, 64));                         \
        mxz = fmaxf(mxz, __shfl_xor(mxz, m, 64));                         \
    }                                                                     \
    if (lane == (k)) { abx0 = mnx; abx1 = mxx; aby0 = mny; aby1 = mxy;    \
                       abz0 = mnz; abz1 = mxz; } }
    REPEAT16(AABBPRE)
#undef AABBPRE
    if (tid < 16) slot4[tid] = 0ull;
    __syncthreads();

    // one-time pin: z values become asm outputs -> cannot be rematerialized
    // as in-loop global reloads (R12 verified registers stay resident).
    asm volatile("" : "+v"(z0), "+v"(z1), "+v"(z2),  "+v"(z3),
                      "+v"(z4), "+v"(z5), "+v"(z6),  "+v"(z7),
                      "+v"(z8), "+v"(z9), "+v"(z10), "+v"(z11),
                      "+v"(z12), "+v"(z13), "+v"(z14), "+v"(z15));

    // ---------- main loop: ONE barrier per iteration ----------
    unsigned long long bkey = 0ull;   // my lane best (max over key0..15)
    int bestk = 0;
    int holder_ln = 0;                // wave-uniform
    float hx = 0.f, hy = 0.f, hz = 0.f;
    float cub = 1e10f;                // lane k: upper bound on chunk max d

    float ccx = bx[0], ccy = bx[1], ccz = bx[2];
    float prev_wd = 1e10f;

    for (int it = 0; it < NPOINT; ++it) {
        if (tid == 0) {
            outc[it * 3 + 0] = ccx;
            outc[it * 3 + 1] = ccy;
            outc[it * 3 + 2] = ccz;
        }

        // --- AABB prune + cub maintenance (lane k -> chunk wv+16k) ---
        bool active = false;
        if (lane < 16) {
            const float dxl = fmaxf(fmaxf(abx0 - ccx, ccx - abx1), 0.0f);
            const float dyl = fmaxf(fmaxf(aby0 - ccy, ccy - aby1), 0.0f);
            const float dzl = fmaxf(fmaxf(abz0 - ccz, ccz - abz1), 0.0f);
            const float mind2 = dxl * dxl + dyl * dyl + dzl * dzl;
            const float bound = fminf(prev_wd, cub);
            active = !(mind2 > bound * 1.001f);
            if (active) {
                const float dxm = fmaxf(ccx - abx0, abx1 - ccx);
                const float dym = fmaxf(ccy - aby0, aby1 - ccy);
                const float dzm = fmaxf(ccz - abz0, abz1 - ccz);
                const float maxd2 = dxm * dxm + dym * dym + dzm * dzm;
                cub = fminf(cub, maxd2);
            }
        }
        const unsigned amask = (unsigned)(__ballot(active) & 0xFFFFull);

        bool lredo = false;
#define UPD(k) if (amask & (1u << (k))) {                                 \
            const int g = wv + ((k) << 4);                                \
            const float2 xy = sxy[(g << 6) + lane];                       \
            const float dx = xy.x - ccx;                                  \
            const float dy = xy.y - ccy;                                  \
            const float dz = z##k - ccz;                                  \
            const float t  = (dx * dx + dy * dy) + dz * dz;               \
            const float dold = __uint_as_float((unsigned)(key##k >> 32)); \
            if (t < dold) {                                               \
                key##k = (((unsigned long long)__float_as_uint(t)) << 32) \
                         | (key##k & 0xFFFFFFFFull);                      \
                lredo |= ((k) == bestk);                                  \
            }                                                             \
        }
        if (amask & 0x000Fu) { UPD(0)  UPD(1)  UPD(2)  UPD(3)  }
        if (amask & 0x00F0u) { UPD(4)  UPD(5)  UPD(6)  UPD(7)  }
        if (amask & 0x0F00u) { UPD(8)  UPD(9)  UPD(10) UPD(11) }
        if (amask & 0xF000u) { UPD(12) UPD(13) UPD(14) UPD(15) }
#undef UPD

        // --- per-lane best: recompute only when invalidated ---
        if (lredo) {
            bkey = 0ull; bestk = 0;
#define LM(k) if (key##k > bkey) { bkey = key##k; bestk = (k); }
            REPEAT16(LM)
#undef LM
        }

        // --- wave best: butterfly only when holder's best decreased ---
        const unsigned long long rb = __ballot(lredo);
        if ((rb >> holder_ln) & 1ull) {
            unsigned long long m = bkey;
            #pragma unroll
            for (int s = 32; s >= 1; s >>= 1) {
                const unsigned long long o = __shfl_xor(m, s, 64);
                m = o > m ? o : m;
            }
            holder_ln = __ffsll((long long)__ballot(bkey == m)) - 1;  // unique
            if (lane == holder_ln) {
                const float2 xy = sxy[((wv + (bestk << 4)) << 6) + lane];
                float zz = z0;
#define ZS(k) zz = (bestk == (k)) ? z##k : zz;
                REPEAT16(ZS)
#undef ZS
                hx = xy.x; hy = xy.y; hz = zz;
            }
        }

        // --- cross-wave: coords write + atomicMax into slot (wv&3) ---
        if (lane == holder_ln) {
            wbc[(it & 1) * 16 + wv] = make_float4(hx, hy, hz, 0.0f);
            atomicMax(&slot4[(it & 3) * 4 + (wv & 3)],
                      bkey | (unsigned long long)wv);
        }
        if (tid < 4) slot4[((it + 1) & 3) * 4 + tid] = 0ull;
        __syncthreads();

        // --- winner: 4 parallel slot reads + spec wbc read + shfl select ---
        const float4 spec = wbc[(it & 1) * 16 + (lane & 15)];
        const unsigned long long s0 = slot4[(it & 3) * 4 + 0];
        const unsigned long long s1 = slot4[(it & 3) * 4 + 1];
        const unsigned long long s2 = slot4[(it & 3) * 4 + 2];
        const unsigned long long s3 = slot4[(it & 3) * 4 + 3];
        unsigned long long wk = s0;
        if (s1 > wk) wk = s1;
        if (s2 > wk) wk = s2;
        if (s3 > wk) wk = s3;
        prev_wd = __uint_as_float((unsigned)(wk >> 32));
        const int wwv = (int)(wk & 0xFull);
        ccx = __shfl(spec.x, wwv, 64);
        ccy = __shfl(spec.y, wwv, 64);
        ccz = __shfl(spec.z, wwv, 64);
    }

    // ---------- flush centroids ----------
    __syncthreads();
    float* outb = new_xyz + (size_t)b * NPOINT * 3;
    #pragma unroll
    for (int j = 0; j < 3; ++j) {
        const int idx = j * FPS_T + tid;
        outb[idx] = outc[idx];
    }
}

// ---------------------------------------------------------------------------
// K2: Ball query. One wave per query; ordered first-32 selection via ballot,
// early exit once 32 found. Exact arithmetic (contract off, rad2 = (float)0.04).
// ---------------------------------------------------------------------------
__global__ __launch_bounds__(256) void ballq_kernel(const float* __restrict__ xyz,
                                                    const float* __restrict__ new_xyz,
                                                    int* __restrict__ gidx) {
    #pragma clang fp contract(off)
    const int lane = threadIdx.x & 63;
    const int q    = blockIdx.x * 4 + (threadIdx.x >> 6);
    const int b    = q >> 10;                  // NPOINT = 1024
    const float* bx = xyz + (size_t)b * NN * 3;
    const float* nx = new_xyz + (size_t)q * 3;
    const float cx = nx[0], cy = nx[1], cz = nx[2];
    const float rad2 = 0.04f;  // f32 cast of python double 0.2**2 — NOT 0.2f*0.2f

    int* out  = gidx + (size_t)q * NSAMPLE;
    int taken = 0;
    int first = NN - 1;

    for (int chunk = 0; chunk < NN / 64 && taken < NSAMPLE; ++chunk) {
        const int   i  = chunk * 64 + lane;
        const float dx = cx - bx[i * 3 + 0];
        const float dy = cy - bx[i * 3 + 1];
        const float dz = cz - bx[i * 3 + 2];
        const float t  = dx * dx + dy * dy + dz * dz;
        const bool ok  = !(t > rad2);
        const unsigned long long m = __ballot(ok);
        const int cnt = __popcll(m);
        if (taken == 0 && cnt > 0) first = chunk * 64 + (__ffsll((long long)m) - 1);
        if (ok) {
            const int rank = taken + __popcll(m & ((1ull << lane) - 1ull));
            if (rank < NSAMPLE) out[rank] = i;
        }
        taken += cnt;
    }
    const int sat = taken < NSAMPLE ? taken : NSAMPLE;
    if (lane >= sat && lane < NSAMPLE) out[lane] = (taken > 0) ? first : (NN - 1);
}

// ---------------------------------------------------------------------------
// K3: gather feats -> LDS, MLP1 (67->64) + relu, MLP2 (64->128) + relu,
// max over the 32 samples. One 256-thread block per query. FMA allowed.
// ---------------------------------------------------------------------------
__global__ __launch_bounds__(256) void mlp_kernel(const float* __restrict__ xyz,
                                                  const float* __restrict__ points,
                                                  const float* __restrict__ w1,
                                                  const float* __restrict__ b1,
                                                  const float* __restrict__ w2,
                                                  const float* __restrict__ b2,
                                                  const float* __restrict__ new_xyz,
                                                  const int*   __restrict__ gidx,
                                                  float* __restrict__ new_points) {
    __shared__ __align__(16) float feats[32][68];
    __shared__ __align__(16) float h1s[32][64];
    __shared__ float pmax[2][128];

    const int q = blockIdx.x;
    const int b = q >> 10;
    const int t = threadIdx.x;

    {
        const int k  = t >> 3;
        const int l8 = t & 7;
        const int gi = gidx[q * 32 + k];
        const float* prow = points + ((size_t)b * NN + gi) * CC;
        const float4 v0 = *(const float4*)(prow + l8 * 8);
        const float4 v1 = *(const float4*)(prow + l8 * 8 + 4);
        *(float4*)&feats[k][4 + l8 * 8] = v0;
        *(float4*)&feats[k][8 + l8 * 8] = v1;
        if (l8 == 0) {
            const float* pr = xyz + ((size_t)b * NN + gi) * 3;
            const float* nr = new_xyz + (size_t)q * 3;
            feats[k][0] = pr[0] - nr[0];
            feats[k][1] = pr[1] - nr[1];
            feats[k][2] = pr[2] - nr[2];
        }
    }

    const int c1 = t & 63;
    float w1r[67];
    #pragma unroll
    for (int j = 0; j < 67; ++j) w1r[j] = w1[c1 * 67 + j];
    const float bb1 = b1[c1];
    __syncthreads();

    const int kg = t >> 6;
    #pragma unroll
    for (int kk = 0; kk < 8; ++kk) {
        const int kr = kg * 8 + kk;
        float acc = bb1;
        acc += feats[kr][0] * w1r[0] + feats[kr][1] * w1r[1] + feats[kr][2] * w1r[2];
        #pragma unroll
        for (int j = 0; j < 64; j += 4) {
            const float4 f = *(const float4*)&feats[kr][4 + j];
            acc += f.x * w1r[3 + j] + f.y * w1r[4 + j] + f.z * w1r[5 + j] + f.w * w1r[6 + j];
        }
        h1s[kr][c1] = fmaxf(acc, 0.0f);
    }

    const int o2 = t & 127;
    const int kh = t >> 7;
    float w2r[64];
    #pragma unroll
    for (int j = 0; j < 64; ++j) w2r[j] = w2[o2 * 64 + j];
    const float bb2 = b2[o2];
    __syncthreads();

    float mx = -INFINITY;
    #pragma unroll
    for (int kk = 0; kk < 16; ++kk) {
        const int kr = kh * 16 + kk;
        float acc = bb2;
        #pragma unroll
        for (int j = 0; j < 64; j += 4) {
            const float4 h = *(const float4*)&h1s[kr][j];
            acc += h.x * w2r[j] + h.y * w2r[j + 1] + h.z * w2r[j + 2] + h.w * w2r[j + 3];
        }
        mx = fmaxf(mx, fmaxf(acc, 0.0f));
    }
    pmax[kh][o2] = mx;
    __syncthreads();
    if (t < 128) {
        new_points[(size_t)q * 128 + t] = fmaxf(pmax[0][t], pmax[1][t]);
    }
}

// ---------------------------------------------------------------------------
extern "C" void kernel_launch(void* const* d_in, const int* in_sizes, int n_in,
                              void* d_out, int out_size, void* d_ws, size_t ws_size,
                              hipStream_t stream) {
    const float* xyz    = (const float*)d_in[0];
    const float* points = (const float*)d_in[1];
    const float* w1     = (const float*)d_in[2];
    const float* b1     = (const float*)d_in[3];
    const float* w2     = (const float*)d_in[4];
    const float* b2     = (const float*)d_in[5];

    float* out_newxyz    = (float*)d_out;
    float* out_newpoints = (float*)d_out + (size_t)BB * NPOINT * 3;
    int*    gidx    = (int*)d_ws;                                   // 512 KB
    float4* sortbuf = (float4*)((char*)d_ws + (size_t)512 * 1024);  // 1 MB

    // LDS map: sxy 131072 | hist/outc alias @131072 (16384) | wbc @147456
    // (512) | slot4 @147968 (128) | wsum @148096 (64)
    const int fps_lds = 148160;
    (void)hipFuncSetAttribute((const void*)fps_kernel,
                              hipFuncAttributeMaxDynamicSharedMemorySize,
                              fps_lds);

    fps_kernel<<<BB, FPS_T, fps_lds, stream>>>(xyz, out_newxyz, sortbuf);
    ballq_kernel<<<(BB * NPOINT) / 4, 256, 0, stream>>>(xyz, out_newxyz, gidx);
    mlp_kernel<<<BB * NPOINT, 256, 0, stream>>>(xyz, points, w1, b1, w2, b2,
                                                out_newxyz, gidx, out_newpoints);
}